// Round 2
// baseline (2136.985 us; speedup 1.0000x reference)
//
#include <hip/hip_runtime.h>
#include <math.h>

#define BB 4
#define CC 128
#define HH 64
#define WW 64
#define LL 4096            // H*W
#define LL2 ((size_t)LL*LL)
#define EPSF 1e-7f
#define NCH 16             // softmax stats chunks over l
#define KS 8               // gemm_out k-slabs

// ---------- K1: bg = fg*(1-m); per-position channel sums ----------
__global__ void prep_kernel(const float* __restrict__ fg, const float* __restrict__ mask,
                            float* __restrict__ bg, float* __restrict__ Sfg,
                            float* __restrict__ Sbg, float* __restrict__ Qq) {
    int g = blockIdx.x * 256 + threadIdx.x;       // B*L threads
    int b = g >> 12, p = g & (LL - 1);
    float mval = mask[g];
    float s = 0.f, sb = 0.f, q = 0.f;
    const float* f = fg + (size_t)b * CC * LL + p;
    float* bgp = bg + (size_t)b * CC * LL + p;
    for (int c = 0; c < CC; ++c) {
        float v = f[(size_t)c * LL];
        s += v;
        float bv = v * (1.f - mval);
        bgp[(size_t)c * LL] = bv;
        sb += bv;
        q += bv * bv;
    }
    Sfg[g] = s; Sbg[g] = sb; Qq[g] = q;
    (void)b;
}

// ---------- K2: inorm[l] = 1/norm, SfgTap[p] = sum of valid Sfg taps ----------
__global__ void norm_kernel(const float* __restrict__ Sfg, const float* __restrict__ Sbg,
                            const float* __restrict__ Qq, float* __restrict__ inorm,
                            float* __restrict__ SfgTap) {
    int g = blockIdx.x * 256 + threadIdx.x;       // B*L
    int b = g >> 12, l = g & (LL - 1);
    int i = l >> 6, j = l & 63;
    float n2 = 9.f * CC * EPSF * EPSF;
    float st = 0.f;
    for (int di = -1; di <= 1; ++di)
        for (int dj = -1; dj <= 1; ++dj) {
            int ii = i + di, jj = j + dj;
            if (ii >= 0 && ii < HH && jj >= 0 && jj < WW) {
                int idx = (b << 12) + (ii << 6) + jj;
                n2 += Qq[idx] + 2.f * EPSF * Sbg[idx];
                st += Sfg[idx];
            }
        }
    inorm[g] = 1.f / sqrtf(n2);
    SfgTap[g] = st;
}

// ---------- K3: M = bg^T @ fg  (inner dim C=128), per sample ----------
__global__ __launch_bounds__(256) void gemm_M(const float* __restrict__ bgb,
                                              const float* __restrict__ fgb,
                                              float* __restrict__ M) {
    __shared__ float As[64][64];
    __shared__ float Bs[64][64];
    int lt = blockIdx.y, pt = blockIdx.x;
    int tid = threadIdx.x, col = tid & 63, rb = tid >> 6;
    int tx = tid & 15, ty = tid >> 4;
    float acc[4][4] = {};
    for (int c0 = 0; c0 < CC; c0 += 64) {
        __syncthreads();
        for (int r = 0; r < 64; r += 4) {
            As[r + rb][col] = bgb[(size_t)(c0 + r + rb) * LL + lt * 64 + col];
            Bs[r + rb][col] = fgb[(size_t)(c0 + r + rb) * LL + pt * 64 + col];
        }
        __syncthreads();
        #pragma unroll 8
        for (int c = 0; c < 64; ++c) {
            float4 a4 = *(const float4*)&As[c][ty * 4];
            float4 b4 = *(const float4*)&Bs[c][tx * 4];
            float av[4] = {a4.x, a4.y, a4.z, a4.w};
            float bv[4] = {b4.x, b4.y, b4.z, b4.w};
            #pragma unroll
            for (int ii = 0; ii < 4; ++ii)
                #pragma unroll
                for (int jj = 0; jj < 4; ++jj)
                    acc[ii][jj] += av[ii] * bv[jj];
        }
    }
    for (int ii = 0; ii < 4; ++ii) {
        float4 v = {acc[ii][0], acc[ii][1], acc[ii][2], acc[ii][3]};
        *(float4*)&M[(size_t)(lt * 64 + ty * 4 + ii) * LL + pt * 64 + tx * 4] = v;
    }
}

// ---------- K4: scores[l,p] = (masked 9-tap diag-sum of M + EPS*SfgTap[p]) * inorm[l] ----------
__global__ void scores_kernel(const float* __restrict__ M, const float* __restrict__ SfgTap,
                              const float* __restrict__ inorm, float* __restrict__ S, int bofs) {
    size_t g = (size_t)blockIdx.x * 256 + threadIdx.x;   // LL2 threads
    int l = (int)(g >> 12), p = (int)(g & 4095);
    int i = l >> 6, j = l & 63, y = p >> 6, x = p & 63;
    float acc = EPSF * SfgTap[bofs + p];
    #pragma unroll
    for (int di = -1; di <= 1; ++di)
        #pragma unroll
        for (int dj = -1; dj <= 1; ++dj) {
            int ii = i + di, jj = j + dj, yy = y + di, xx = x + dj;
            if (ii >= 0 && ii < HH && jj >= 0 && jj < WW && yy >= 0 && yy < HH && xx >= 0 && xx < WW) {
                int d = di * 64 + dj;
                acc += M[(size_t)(l + d) * LL + (p + d)];
            }
        }
    S[g] = acc * inorm[bofs + l];
}

// ---------- K5: per-column online softmax stats over box-summed scores (chunked over l) ----------
__global__ void stats_kernel(const float* __restrict__ S, const float* __restrict__ inorm,
                             float* __restrict__ maxc, float* __restrict__ sumc,
                             float* __restrict__ wsumc, int bofs) {
    int pt = blockIdx.x, ch = blockIdx.y;
    int lane = threadIdx.x & 63, grp = threadIdx.x >> 6;
    int p = pt * 64 + lane;
    int y = p >> 6, x = p & 63;
    float mx = -1e30f, se = 0.f, ws = 0.f;
    int l0 = ch * (LL / NCH);
    for (int l = l0 + grp; l < l0 + (LL / NCH); l += 4) {
        float bs = 0.f;
        #pragma unroll
        for (int gy = -1; gy <= 1; ++gy) {
            int yy = y + gy;
            if (yy < 0 || yy >= HH) continue;
            #pragma unroll
            for (int gx = -1; gx <= 1; ++gx) {
                int xx = x + gx;
                if (xx < 0 || xx >= WW) continue;
                bs += S[(size_t)l * LL + (yy << 6) + xx];
            }
        }
        float in = inorm[bofs + l];
        if (bs > mx) {
            float r = expf(mx - bs);
            se = se * r + 1.f;
            ws = ws * r + in;
            mx = bs;
        } else {
            float e = expf(bs - mx);
            se += e; ws += e * in;
        }
    }
    __shared__ float smx[4][64], sse[4][64], sws[4][64];
    smx[grp][lane] = mx; sse[grp][lane] = se; sws[grp][lane] = ws;
    __syncthreads();
    if (grp == 0) {
        for (int k = 1; k < 4; ++k) {
            float m2 = smx[k][lane], s2 = sse[k][lane], w2 = sws[k][lane];
            float nm = fmaxf(mx, m2);
            float r1 = expf(mx - nm), r2 = expf(m2 - nm);
            se = se * r1 + s2 * r2;
            ws = ws * r1 + w2 * r2;
            mx = nm;
        }
        int idx = ch * LL + p;
        maxc[idx] = mx; sumc[idx] = se; wsumc[idx] = ws;
    }
}

// ---------- K5b: combine chunk stats ----------
__global__ void combine_kernel(const float* __restrict__ maxc, const float* __restrict__ sumc,
                               const float* __restrict__ wsumc, float* __restrict__ maxv,
                               float* __restrict__ sumexp, float* __restrict__ Bsum) {
    int p = blockIdx.x * 256 + threadIdx.x;   // L
    float mx = -1e30f, se = 0.f, ws = 0.f;
    for (int ch = 0; ch < NCH; ++ch) {
        int idx = ch * LL + p;
        float m2 = maxc[idx], s2 = sumc[idx], w2 = wsumc[idx];
        float nm = fmaxf(mx, m2);
        float r1 = expf(mx - nm), r2 = expf(m2 - nm);
        se = se * r1 + s2 * r2;
        ws = ws * r1 + w2 * r2;
        mx = nm;
    }
    maxv[p] = mx; sumexp[p] = se; Bsum[p] = ws / se;
}

// ---------- K6: T[p] = sum of valid Bsum taps ----------
__global__ void ttap_kernel(const float* __restrict__ Bsum, float* __restrict__ Tp) {
    int p = blockIdx.x * 256 + threadIdx.x;
    int y = p >> 6, x = p & 63;
    float t = 0.f;
    for (int gy = -1; gy <= 1; ++gy) {
        int yy = y + gy;
        if (yy < 0 || yy >= HH) continue;
        for (int gx = -1; gx <= 1; ++gx) {
            int xx = x + gx;
            if (xx < 0 || xx >= WW) continue;
            t += Bsum[(yy << 6) + xx];
        }
    }
    Tp[p] = t;
}

// ---------- K7: b[l,p] = exp(box(scores)-max)/sumexp * inorm[l] ----------
__global__ void writeb_kernel(const float* __restrict__ S, const float* __restrict__ maxv,
                              const float* __restrict__ sumexp, const float* __restrict__ inorm,
                              float* __restrict__ Bb, int bofs) {
    size_t g = (size_t)blockIdx.x * 256 + threadIdx.x;
    int l = (int)(g >> 12), p = (int)(g & 4095);
    int y = p >> 6, x = p & 63;
    float bs = 0.f;
    #pragma unroll
    for (int gy = -1; gy <= 1; ++gy) {
        int yy = y + gy;
        if (yy < 0 || yy >= HH) continue;
        #pragma unroll
        for (int gx = -1; gx <= 1; ++gx) {
            int xx = x + gx;
            if (xx < 0 || xx >= WW) continue;
            bs += S[(size_t)l * LL + (yy << 6) + xx];
        }
    }
    Bb[g] = expf(bs - maxv[p]) / sumexp[p] * inorm[bofs + l];
}

// ---------- K8: N[l,p] = masked 9-tap diag-sum of b ----------
__global__ void nshift_kernel(const float* __restrict__ Bb, float* __restrict__ Nn) {
    size_t g = (size_t)blockIdx.x * 256 + threadIdx.x;
    int l = (int)(g >> 12), p = (int)(g & 4095);
    int i = l >> 6, j = l & 63, y = p >> 6, x = p & 63;
    float acc = 0.f;
    #pragma unroll
    for (int di = -1; di <= 1; ++di)
        #pragma unroll
        for (int dj = -1; dj <= 1; ++dj) {
            int ii = i + di, jj = j + dj, yy = y + di, xx = x + dj;
            if (ii >= 0 && ii < HH && jj >= 0 && jj < WW && yy >= 0 && yy < HH && xx >= 0 && xx < WW) {
                int d = di * 64 + dj;
                acc += Bb[(size_t)(l + d) * LL + (p + d)];
            }
        }
    Nn[g] = acc;
}

// ---------- K9a: partial rec = bg @ N over a k-slab ----------
__global__ __launch_bounds__(256) void gemm_out_part(const float* __restrict__ bgb,
                                                     const float* __restrict__ Nn,
                                                     float* __restrict__ part) {
    __shared__ float As[CC][64];   // 32KB (c,k)
    __shared__ float Ns[64][64];   // 16KB (k,p)
    int pt = blockIdx.x, ks = blockIdx.y;
    int tid = threadIdx.x, col = tid & 63, rb = tid >> 6;
    int tx = tid & 15, ty = tid >> 4;
    float acc[8][4] = {};
    for (int kt = ks * (LL / KS); kt < (ks + 1) * (LL / KS); kt += 64) {
        __syncthreads();
        for (int r = 0; r < CC; r += 4)
            As[r + rb][col] = bgb[(size_t)(r + rb) * LL + kt + col];
        for (int r = 0; r < 64; r += 4)
            Ns[r + rb][col] = Nn[(size_t)(kt + r + rb) * LL + pt * 64 + col];
        __syncthreads();
        #pragma unroll 4
        for (int kk = 0; kk < 64; ++kk) {
            float4 b4 = *(const float4*)&Ns[kk][tx * 4];
            float bv[4] = {b4.x, b4.y, b4.z, b4.w};
            #pragma unroll
            for (int ii = 0; ii < 8; ++ii) {
                float a = As[ty * 8 + ii][kk];
                #pragma unroll
                for (int jj = 0; jj < 4; ++jj)
                    acc[ii][jj] += a * bv[jj];
            }
        }
    }
    for (int ii = 0; ii < 8; ++ii) {
        float4 v = {acc[ii][0], acc[ii][1], acc[ii][2], acc[ii][3]};
        *(float4*)&part[((size_t)ks * CC + ty * 8 + ii) * LL + pt * 64 + tx * 4] = v;
    }
}

// ---------- K9b: combine slabs + epilogue ----------
__global__ void epilogue_kernel(const float* __restrict__ part, const float* __restrict__ Tp,
                                const float* __restrict__ fgb, const float* __restrict__ maskb,
                                float* __restrict__ outb) {
    int g = blockIdx.x * 256 + threadIdx.x;   // C*L
    int p = g & 4095;
    float acc = 0.f;
    for (int ks = 0; ks < KS; ++ks)
        acc += part[(size_t)ks * CC * LL + g];
    float rec = acc + EPSF * Tp[p];
    float mval = maskb[p];
    outb[g] = rec * mval * (1.f / 9.f) + fgb[g] * (1.f - mval);
}

extern "C" void kernel_launch(void* const* d_in, const int* in_sizes, int n_in,
                              void* d_out, int out_size, void* d_ws, size_t ws_size,
                              hipStream_t stream) {
    const float* fg = (const float*)d_in[0];     // [B,C,H,W]
    const float* mask = (const float*)d_in[1];   // [B,1,H,W]
    float* out = (float*)d_out;
    float* ws = (float*)d_ws;

    // ws layout (floats); total ~138 MiB
    float* bg = ws;                                  // B*C*L
    float* Sfg = bg + (size_t)BB * CC * LL;          // B*L each:
    float* Sbg = Sfg + BB * LL;
    float* Qq = Sbg + BB * LL;
    float* inorm = Qq + BB * LL;
    float* SfgTap = inorm + BB * LL;
    float* maxc = SfgTap + BB * LL;                  // NCH*L each (per-sample reuse):
    float* sumc = maxc + NCH * LL;
    float* wsumc = sumc + NCH * LL;
    float* maxv = wsumc + NCH * LL;                  // L each:
    float* sumexp = maxv + LL;
    float* Bsum = sumexp + LL;
    float* Tp = Bsum + LL;
    float* bufA = Tp + LL;                           // LL2
    float* bufB = bufA + LL2;                        // LL2

    prep_kernel<<<BB * LL / 256, 256, 0, stream>>>(fg, mask, bg, Sfg, Sbg, Qq);
    norm_kernel<<<BB * LL / 256, 256, 0, stream>>>(Sfg, Sbg, Qq, inorm, SfgTap);

    for (int b = 0; b < BB; ++b) {
        const float* fgb = fg + (size_t)b * CC * LL;
        const float* bgb = bg + (size_t)b * CC * LL;
        const float* mb = mask + (size_t)b * LL;
        int bofs = b * LL;

        gemm_M<<<dim3(64, 64), 256, 0, stream>>>(bgb, fgb, bufA);
        scores_kernel<<<65536, 256, 0, stream>>>(bufA, SfgTap, inorm, bufB, bofs);
        stats_kernel<<<dim3(64, NCH), 256, 0, stream>>>(bufB, inorm, maxc, sumc, wsumc, bofs);
        combine_kernel<<<LL / 256, 256, 0, stream>>>(maxc, sumc, wsumc, maxv, sumexp, Bsum);
        ttap_kernel<<<LL / 256, 256, 0, stream>>>(Bsum, Tp);
        writeb_kernel<<<65536, 256, 0, stream>>>(bufB, maxv, sumexp, inorm, bufA, bofs);
        nshift_kernel<<<65536, 256, 0, stream>>>(bufA, bufB);
        gemm_out_part<<<dim3(64, KS), 256, 0, stream>>>(bgb, bufB, bufA);
        epilogue_kernel<<<CC * LL / 256, 256, 0, stream>>>(bufA, Tp, fgb, mb, out + (size_t)b * CC * LL);
    }
}

// Round 3
// 1593.222 us; speedup vs baseline: 1.3413x; 1.3413x over previous
//
#include <hip/hip_runtime.h>
#include <math.h>

#define BB 4
#define CC 128
#define HH 64
#define WW 64
#define LL 4096            // H*W
#define LL2 ((size_t)LL*LL)
#define EPSF 1e-7f
#define NCH 16             // softmax stats chunks over l
#define KS 8               // gemm_out k-slabs

// ---------- K1: bg = fg*(1-m); per-position channel sums ----------
__global__ void prep_kernel(const float* __restrict__ fg, const float* __restrict__ mask,
                            float* __restrict__ bg, float* __restrict__ Sfg,
                            float* __restrict__ Sbg, float* __restrict__ Qq) {
    int g = blockIdx.x * 256 + threadIdx.x;       // B*L threads
    int b = g >> 12, p = g & (LL - 1);
    float mval = mask[g];
    float s = 0.f, sb = 0.f, q = 0.f;
    const float* f = fg + (size_t)b * CC * LL + p;
    float* bgp = bg + (size_t)b * CC * LL + p;
    for (int c = 0; c < CC; ++c) {
        float v = f[(size_t)c * LL];
        s += v;
        float bv = v * (1.f - mval);
        bgp[(size_t)c * LL] = bv;
        sb += bv;
        q += bv * bv;
    }
    Sfg[g] = s; Sbg[g] = sb; Qq[g] = q;
}

// ---------- K2: inorm[l] = 1/norm, SfgTap[p] = sum of valid Sfg taps ----------
__global__ void norm_kernel(const float* __restrict__ Sfg, const float* __restrict__ Sbg,
                            const float* __restrict__ Qq, float* __restrict__ inorm,
                            float* __restrict__ SfgTap) {
    int g = blockIdx.x * 256 + threadIdx.x;       // B*L
    int b = g >> 12, l = g & (LL - 1);
    int i = l >> 6, j = l & 63;
    float n2 = 9.f * CC * EPSF * EPSF;
    float st = 0.f;
    for (int di = -1; di <= 1; ++di)
        for (int dj = -1; dj <= 1; ++dj) {
            int ii = i + di, jj = j + dj;
            if (ii >= 0 && ii < HH && jj >= 0 && jj < WW) {
                int idx = (b << 12) + (ii << 6) + jj;
                n2 += Qq[idx] + 2.f * EPSF * Sbg[idx];
                st += Sfg[idx];
            }
        }
    inorm[g] = 1.f / sqrtf(n2);
    SfgTap[g] = st;
}

// ---------- K3: M = bg^T @ fg  (inner dim C=128), per sample ----------
__global__ __launch_bounds__(256) void gemm_M(const float* __restrict__ bgb,
                                              const float* __restrict__ fgb,
                                              float* __restrict__ M) {
    __shared__ float As[64][64];
    __shared__ float Bs[64][64];
    int lt = blockIdx.y, pt = blockIdx.x;
    int tid = threadIdx.x, col = tid & 63, rb = tid >> 6;
    int tx = tid & 15, ty = tid >> 4;
    float acc[4][4] = {};
    for (int c0 = 0; c0 < CC; c0 += 64) {
        __syncthreads();
        for (int r = 0; r < 64; r += 4) {
            As[r + rb][col] = bgb[(size_t)(c0 + r + rb) * LL + lt * 64 + col];
            Bs[r + rb][col] = fgb[(size_t)(c0 + r + rb) * LL + pt * 64 + col];
        }
        __syncthreads();
        #pragma unroll 8
        for (int c = 0; c < 64; ++c) {
            float4 a4 = *(const float4*)&As[c][ty * 4];
            float4 b4 = *(const float4*)&Bs[c][tx * 4];
            float av[4] = {a4.x, a4.y, a4.z, a4.w};
            float bv[4] = {b4.x, b4.y, b4.z, b4.w};
            #pragma unroll
            for (int ii = 0; ii < 4; ++ii)
                #pragma unroll
                for (int jj = 0; jj < 4; ++jj)
                    acc[ii][jj] += av[ii] * bv[jj];
        }
    }
    for (int ii = 0; ii < 4; ++ii) {
        float4 v = {acc[ii][0], acc[ii][1], acc[ii][2], acc[ii][3]};
        *(float4*)&M[(size_t)(lt * 64 + ty * 4 + ii) * LL + pt * 64 + tx * 4] = v;
    }
}

// ---------- K4: SB[l,:] = box_p( (9-tap diag-sum of M + EPS*SfgTap)*inorm[l] ) ----------
// one block per l-row; S row staged in LDS, box-summed from LDS.
__global__ __launch_bounds__(256) void scoresbox_kernel(const float* __restrict__ M,
                                                        const float* __restrict__ SfgTap,
                                                        const float* __restrict__ inorm,
                                                        float* __restrict__ SB, int bofs) {
    __shared__ float srow[LL];    // 16 KiB
    int l = blockIdx.x;
    int i = l >> 6, j = l & 63;
    float inl = inorm[bofs + l];
    for (int p = threadIdx.x; p < LL; p += 256) {
        int y = p >> 6, x = p & 63;
        float acc = EPSF * SfgTap[bofs + p];
        #pragma unroll
        for (int di = -1; di <= 1; ++di)
            #pragma unroll
            for (int dj = -1; dj <= 1; ++dj) {
                int ii = i + di, jj = j + dj, yy = y + di, xx = x + dj;
                if (ii >= 0 && ii < HH && jj >= 0 && jj < WW && yy >= 0 && yy < HH && xx >= 0 && xx < WW) {
                    int d = di * 64 + dj;
                    acc += M[(size_t)(l + d) * LL + (p + d)];
                }
            }
        srow[p] = acc * inl;
    }
    __syncthreads();
    for (int p = threadIdx.x; p < LL; p += 256) {
        int y = p >> 6, x = p & 63;
        float bs = 0.f;
        #pragma unroll
        for (int gy = -1; gy <= 1; ++gy) {
            int yy = y + gy;
            if (yy < 0 || yy >= HH) continue;
            #pragma unroll
            for (int gx = -1; gx <= 1; ++gx) {
                int xx = x + gx;
                if (xx < 0 || xx >= WW) continue;
                bs += srow[(yy << 6) + xx];
            }
        }
        SB[(size_t)l * LL + p] = bs;
    }
}

// ---------- K5: per-column online softmax stats over SB (1 load/elem, chunked over l) ----------
__global__ __launch_bounds__(256) void stats2_kernel(const float* __restrict__ SB,
                                                     const float* __restrict__ inorm,
                                                     float* __restrict__ maxc, float* __restrict__ sumc,
                                                     float* __restrict__ wsumc, int bofs) {
    int pt = blockIdx.x, ch = blockIdx.y;
    int lane = threadIdx.x & 63, grp = threadIdx.x >> 6;
    int p = pt * 64 + lane;
    float mx = -1e30f, se = 0.f, ws = 0.f;
    int l0 = ch * (LL / NCH);
    for (int l = l0 + grp; l < l0 + (LL / NCH); l += 4) {
        float bs = SB[(size_t)l * LL + p];
        float in = inorm[bofs + l];
        float nm = fmaxf(mx, bs);
        float r1 = __expf(mx - nm), r2 = __expf(bs - nm);
        se = se * r1 + r2;
        ws = ws * r1 + r2 * in;
        mx = nm;
    }
    __shared__ float smx[4][64], sse[4][64], sws[4][64];
    smx[grp][lane] = mx; sse[grp][lane] = se; sws[grp][lane] = ws;
    __syncthreads();
    if (grp == 0) {
        for (int k = 1; k < 4; ++k) {
            float m2 = smx[k][lane], s2 = sse[k][lane], w2 = sws[k][lane];
            float nm = fmaxf(mx, m2);
            float r1 = __expf(mx - nm), r2 = __expf(m2 - nm);
            se = se * r1 + s2 * r2;
            ws = ws * r1 + w2 * r2;
            mx = nm;
        }
        int idx = ch * LL + p;
        maxc[idx] = mx; sumc[idx] = se; wsumc[idx] = ws;
    }
}

// ---------- K5b: combine chunk stats + T taps, single block ----------
__global__ __launch_bounds__(1024) void combine_ttap_kernel(const float* __restrict__ maxc,
                                                            const float* __restrict__ sumc,
                                                            const float* __restrict__ wsumc,
                                                            float* __restrict__ maxv,
                                                            float* __restrict__ invsum,
                                                            float* __restrict__ Tp) {
    __shared__ float bsum[LL];    // 16 KiB
    int t = threadIdx.x;
    for (int k = 0; k < 4; ++k) {
        int p = t + k * 1024;
        float mx = -1e30f, se = 0.f, ws = 0.f;
        for (int ch = 0; ch < NCH; ++ch) {
            int idx = ch * LL + p;
            float m2 = maxc[idx], s2 = sumc[idx], w2 = wsumc[idx];
            float nm = fmaxf(mx, m2);
            float r1 = __expf(mx - nm), r2 = __expf(m2 - nm);
            se = se * r1 + s2 * r2;
            ws = ws * r1 + w2 * r2;
            mx = nm;
        }
        maxv[p] = mx;
        invsum[p] = 1.f / se;
        bsum[p] = ws / se;
    }
    __syncthreads();
    for (int k = 0; k < 4; ++k) {
        int p = t + k * 1024;
        int y = p >> 6, x = p & 63;
        float tt = 0.f;
        for (int gy = -1; gy <= 1; ++gy) {
            int yy = y + gy;
            if (yy < 0 || yy >= HH) continue;
            for (int gx = -1; gx <= 1; ++gx) {
                int xx = x + gx;
                if (xx < 0 || xx >= WW) continue;
                tt += bsum[(yy << 6) + xx];
            }
        }
        Tp[p] = tt;
    }
}

// ---------- K7: fused softmax-apply + 9-tap diag shift: Nn directly from SB ----------
__global__ __launch_bounds__(256) void bnfuse_kernel(const float* __restrict__ SB,
                                                     const float* __restrict__ maxv,
                                                     const float* __restrict__ invsum,
                                                     const float* __restrict__ inorm,
                                                     float* __restrict__ Nn, int bofs) {
    int l = blockIdx.x;
    int i = l >> 6, j = l & 63;
    for (int p = threadIdx.x; p < LL; p += 256) {
        int y = p >> 6, x = p & 63;
        float acc = 0.f;
        #pragma unroll
        for (int di = -1; di <= 1; ++di)
            #pragma unroll
            for (int dj = -1; dj <= 1; ++dj) {
                int ii = i + di, jj = j + dj, yy = y + di, xx = x + dj;
                if (ii >= 0 && ii < HH && jj >= 0 && jj < WW && yy >= 0 && yy < HH && xx >= 0 && xx < WW) {
                    int d = di * 64 + dj;
                    int pd = p + d;
                    float e = __expf(SB[(size_t)(l + d) * LL + pd] - maxv[pd]);
                    acc += e * invsum[pd] * inorm[bofs + l + d];
                }
            }
        Nn[(size_t)l * LL + p] = acc;
    }
}

// ---------- K9a: partial rec = bg @ N over a k-slab ----------
__global__ __launch_bounds__(256) void gemm_out_part(const float* __restrict__ bgb,
                                                     const float* __restrict__ Nn,
                                                     float* __restrict__ part) {
    __shared__ float As[CC][64];   // 32KB (c,k)
    __shared__ float Ns[64][64];   // 16KB (k,p)
    int pt = blockIdx.x, ks = blockIdx.y;
    int tid = threadIdx.x, col = tid & 63, rb = tid >> 6;
    int tx = tid & 15, ty = tid >> 4;
    float acc[8][4] = {};
    for (int kt = ks * (LL / KS); kt < (ks + 1) * (LL / KS); kt += 64) {
        __syncthreads();
        for (int r = 0; r < CC; r += 4)
            As[r + rb][col] = bgb[(size_t)(r + rb) * LL + kt + col];
        for (int r = 0; r < 64; r += 4)
            Ns[r + rb][col] = Nn[(size_t)(kt + r + rb) * LL + pt * 64 + col];
        __syncthreads();
        #pragma unroll 4
        for (int kk = 0; kk < 64; ++kk) {
            float4 b4 = *(const float4*)&Ns[kk][tx * 4];
            float bv[4] = {b4.x, b4.y, b4.z, b4.w};
            #pragma unroll
            for (int ii = 0; ii < 8; ++ii) {
                float a = As[ty * 8 + ii][kk];
                #pragma unroll
                for (int jj = 0; jj < 4; ++jj)
                    acc[ii][jj] += a * bv[jj];
            }
        }
    }
    for (int ii = 0; ii < 8; ++ii) {
        float4 v = {acc[ii][0], acc[ii][1], acc[ii][2], acc[ii][3]};
        *(float4*)&part[((size_t)ks * CC + ty * 8 + ii) * LL + pt * 64 + tx * 4] = v;
    }
}

// ---------- K9b: combine slabs + epilogue ----------
__global__ void epilogue_kernel(const float* __restrict__ part, const float* __restrict__ Tp,
                                const float* __restrict__ fgb, const float* __restrict__ maskb,
                                float* __restrict__ outb) {
    int g = blockIdx.x * 256 + threadIdx.x;   // C*L
    int p = g & 4095;
    float acc = 0.f;
    for (int ks = 0; ks < KS; ++ks)
        acc += part[(size_t)ks * CC * LL + g];
    float rec = acc + EPSF * Tp[p];
    float mval = maskb[p];
    outb[g] = rec * mval * (1.f / 9.f) + fgb[g] * (1.f - mval);
}

extern "C" void kernel_launch(void* const* d_in, const int* in_sizes, int n_in,
                              void* d_out, int out_size, void* d_ws, size_t ws_size,
                              hipStream_t stream) {
    const float* fg = (const float*)d_in[0];     // [B,C,H,W]
    const float* mask = (const float*)d_in[1];   // [B,1,H,W]
    float* out = (float*)d_out;
    float* ws = (float*)d_ws;

    // ws layout (floats); total ~138 MiB
    float* bg = ws;                                  // B*C*L
    float* Sfg = bg + (size_t)BB * CC * LL;          // B*L each:
    float* Sbg = Sfg + BB * LL;
    float* Qq = Sbg + BB * LL;
    float* inorm = Qq + BB * LL;
    float* SfgTap = inorm + BB * LL;
    float* maxc = SfgTap + BB * LL;                  // NCH*L each (per-sample reuse):
    float* sumc = maxc + NCH * LL;
    float* wsumc = sumc + NCH * LL;
    float* maxv = wsumc + NCH * LL;                  // L each:
    float* invsum = maxv + LL;
    float* Tp = invsum + LL;
    float* bufA = Tp + LL;                           // LL2
    float* bufB = bufA + LL2;                        // LL2

    prep_kernel<<<BB * LL / 256, 256, 0, stream>>>(fg, mask, bg, Sfg, Sbg, Qq);
    norm_kernel<<<BB * LL / 256, 256, 0, stream>>>(Sfg, Sbg, Qq, inorm, SfgTap);

    for (int b = 0; b < BB; ++b) {
        const float* fgb = fg + (size_t)b * CC * LL;
        const float* bgb = bg + (size_t)b * CC * LL;
        const float* mb = mask + (size_t)b * LL;
        int bofs = b * LL;

        gemm_M<<<dim3(64, 64), 256, 0, stream>>>(bgb, fgb, bufA);
        scoresbox_kernel<<<LL, 256, 0, stream>>>(bufA, SfgTap, inorm, bufB, bofs);
        stats2_kernel<<<dim3(64, NCH), 256, 0, stream>>>(bufB, inorm, maxc, sumc, wsumc, bofs);
        combine_ttap_kernel<<<1, 1024, 0, stream>>>(maxc, sumc, wsumc, maxv, invsum, Tp);
        bnfuse_kernel<<<LL, 256, 0, stream>>>(bufB, maxv, invsum, inorm, bufA, bofs);
        gemm_out_part<<<dim3(64, KS), 256, 0, stream>>>(bgb, bufA, bufB);
        epilogue_kernel<<<CC * LL / 256, 256, 0, stream>>>(bufB, Tp, fgb, mb, out + (size_t)b * CC * LL);
    }
}

// Round 4
// 1010.798 us; speedup vs baseline: 2.1142x; 1.5762x over previous
//
#include <hip/hip_runtime.h>
#include <math.h>

#define BB 4
#define CC 128
#define HH 64
#define WW 64
#define LL 4096            // H*W
#define LL2 ((size_t)LL*LL)
#define EPSF 1e-7f
#define NCH 16             // softmax stats chunks over l
#define KS 8               // gemm_out k-slabs

typedef __attribute__((ext_vector_type(8))) short s8v;    // 8 bf16 (4 VGPRs)
typedef __attribute__((ext_vector_type(4))) float f4v;    // 4 fp32

struct f4u { float v[4]; };   // align 4: legal unaligned-by-16 vector load

__device__ __forceinline__ ushort f2bf(float f) {
    union { float f; unsigned u; } x; x.f = f;
    unsigned r = x.u + 0x7FFFu + ((x.u >> 16) & 1u);   // RNE
    return (ushort)(r >> 16);
}
__device__ __forceinline__ float bf2f(ushort u) {
    union { unsigned u; float f; } x; x.u = ((unsigned)u) << 16;
    return x.f;
}

// ---------- K1: per-position channel sums (bg computed inline) ----------
__global__ void prep_kernel(const float* __restrict__ fg, const float* __restrict__ mask,
                            float* __restrict__ Sfg, float* __restrict__ Sbg,
                            float* __restrict__ Qq) {
    int g = blockIdx.x * 256 + threadIdx.x;       // B*L threads
    int b = g >> 12, p = g & (LL - 1);
    float mval = mask[g];
    float s = 0.f, sb = 0.f, q = 0.f;
    const float* f = fg + (size_t)b * CC * LL + p;
    for (int c = 0; c < CC; ++c) {
        float v = f[(size_t)c * LL];
        s += v;
        float bv = v * (1.f - mval);
        sb += bv;
        q += bv * bv;
    }
    Sfg[g] = s; Sbg[g] = sb; Qq[g] = q;
}

// ---------- K2: inorm[l] = 1/norm, SfgTap[p] = sum of valid Sfg taps ----------
__global__ void norm_kernel(const float* __restrict__ Sfg, const float* __restrict__ Sbg,
                            const float* __restrict__ Qq, float* __restrict__ inorm,
                            float* __restrict__ SfgTap) {
    int g = blockIdx.x * 256 + threadIdx.x;       // B*L
    int b = g >> 12, l = g & (LL - 1);
    int i = l >> 6, j = l & 63;
    float n2 = 9.f * CC * EPSF * EPSF;
    float st = 0.f;
    for (int di = -1; di <= 1; ++di)
        for (int dj = -1; dj <= 1; ++dj) {
            int ii = i + di, jj = j + dj;
            if (ii >= 0 && ii < HH && jj >= 0 && jj < WW) {
                int idx = (b << 12) + (ii << 6) + jj;
                n2 += Qq[idx] + 2.f * EPSF * Sbg[idx];
                st += Sfg[idx];
            }
        }
    inorm[g] = 1.f / sqrtf(n2);
    SfgTap[g] = st;
}

// ---------- K2b: per-sample bf16 copies: fgT/bgT [L][C] (transposed), bgH [C][L] ----------
__global__ __launch_bounds__(256) void transpose_kernel(const float* __restrict__ fgb,
                                                        const float* __restrict__ maskb,
                                                        ushort* __restrict__ fgT,
                                                        ushort* __restrict__ bgT,
                                                        ushort* __restrict__ bgH) {
    __shared__ float tile[64][65];
    int l0 = blockIdx.x * 64, c0 = blockIdx.y * 64;
    int tid = threadIdx.x, col = tid & 63, r0 = tid >> 6;
    for (int r = r0; r < 64; r += 4) {
        float v = fgb[(size_t)(c0 + r) * LL + l0 + col];
        tile[r][col] = v;
        bgH[(size_t)(c0 + r) * LL + l0 + col] = f2bf(v * (1.f - maskb[l0 + col]));
    }
    __syncthreads();
    for (int idx = tid; idx < 4096; idx += 256) {
        int row = idx >> 6;     // l offset
        int c = idx & 63;       // c offset
        float v = tile[c][row];
        size_t o = (size_t)(l0 + row) * CC + c0 + c;
        fgT[o] = f2bf(v);
        bgT[o] = f2bf(v * (1.f - maskb[l0 + row]));
    }
}

// ---------- K3: M = bg^T @ fg via MFMA bf16. A=bgT[L][C], B^T=fgT[L][C] ----------
__global__ __launch_bounds__(256) void gemm_M_mfma(const ushort* __restrict__ bgT,
                                                   const ushort* __restrict__ fgT,
                                                   float* __restrict__ M) {
    int lt = blockIdx.y, pt = blockIdx.x;            // 32x32 tiles of 128x128
    int wid = threadIdx.x >> 6, lane = threadIdx.x & 63;
    int wm = wid >> 1, wn = wid & 1;                 // 2x2 waves
    int lm = lane & 15, lk = lane >> 4;
    f4v acc[4][4] = {};
    int arow = lt * 128 + wm * 64 + lm;
    int brow = pt * 128 + wn * 64 + lm;
    for (int k0 = 0; k0 < CC; k0 += 32) {
        s8v a[4], bq[4];
        #pragma unroll
        for (int f = 0; f < 4; ++f)
            a[f] = *(const s8v*)(bgT + (size_t)(arow + f * 16) * CC + k0 + lk * 8);
        #pragma unroll
        for (int f = 0; f < 4; ++f)
            bq[f] = *(const s8v*)(fgT + (size_t)(brow + f * 16) * CC + k0 + lk * 8);
        #pragma unroll
        for (int mi = 0; mi < 4; ++mi)
            #pragma unroll
            for (int ni = 0; ni < 4; ++ni)
                acc[mi][ni] = __builtin_amdgcn_mfma_f32_16x16x32_bf16(a[mi], bq[ni], acc[mi][ni], 0, 0, 0);
    }
    #pragma unroll
    for (int mi = 0; mi < 4; ++mi)
        #pragma unroll
        for (int ni = 0; ni < 4; ++ni)
            #pragma unroll
            for (int r = 0; r < 4; ++r)
                M[(size_t)(lt * 128 + wm * 64 + mi * 16 + lk * 4 + r) * LL
                  + pt * 128 + wn * 64 + ni * 16 + lm] = acc[mi][ni][r];
}

// ---------- K4: SB[l,:] = box_p( (9-tap diag-sum of M + EPS*SfgTap)*inorm[l] ), 4-wide ----------
__global__ __launch_bounds__(256) void scoresbox_kernel(const float* __restrict__ M,
                                                        const float* __restrict__ SfgTap,
                                                        const float* __restrict__ inorm,
                                                        float* __restrict__ SB, int bofs) {
    __shared__ float srow[LL + 136];
    float* sr = srow + 68;
    int l = blockIdx.x;
    int i = l >> 6, j = l & 63;
    float inl = inorm[bofs + l];
    for (int it = 0; it < 4; ++it) {
        int p = 4 * (threadIdx.x + it * 256);
        int y = p >> 6, x0 = p & 63;
        bool e0 = (x0 == 0), e3 = (x0 == 60);
        f4u t = *(const f4u*)(SfgTap + bofs + p);
        float s0 = EPSF * t.v[0], s1 = EPSF * t.v[1], s2 = EPSF * t.v[2], s3 = EPSF * t.v[3];
        #pragma unroll
        for (int di = -1; di <= 1; ++di) {
            int ii = i + di, yy = y + di;
            if ((unsigned)ii >= HH || (unsigned)yy >= HH) continue;
            #pragma unroll
            for (int dj = -1; dj <= 1; ++dj) {
                int jj = j + dj;
                if ((unsigned)jj >= WW) continue;
                int D = di * 64 + dj;
                f4u v = *(const f4u*)(M + (size_t)(l + D) * LL + (p + D));
                float v0 = v.v[0], v3 = v.v[3];
                if (dj == -1) v0 = e0 ? 0.f : v0;
                if (dj == 1)  v3 = e3 ? 0.f : v3;
                s0 += v0; s1 += v.v[1]; s2 += v.v[2]; s3 += v3;
            }
        }
        f4u o; o.v[0] = s0 * inl; o.v[1] = s1 * inl; o.v[2] = s2 * inl; o.v[3] = s3 * inl;
        *(f4u*)(sr + p) = o;
    }
    __syncthreads();
    for (int it = 0; it < 4; ++it) {
        int p = 4 * (threadIdx.x + it * 256);
        int y = p >> 6, x0 = p & 63;
        bool e0 = (x0 == 0), e3 = (x0 == 60);
        float b0 = 0.f, b1 = 0.f, b2 = 0.f, b3 = 0.f;
        #pragma unroll
        for (int gy = -1; gy <= 1; ++gy) {
            int yy = y + gy;
            if ((unsigned)yy >= HH) continue;
            int base = (yy << 6) + x0;
            float m1 = sr[base - 1], c0 = sr[base], c1 = sr[base + 1];
            float c2 = sr[base + 2], c3 = sr[base + 3], p4 = sr[base + 4];
            b0 += (e0 ? 0.f : m1) + c0 + c1;
            b1 += c0 + c1 + c2;
            b2 += c1 + c2 + c3;
            b3 += c2 + c3 + (e3 ? 0.f : p4);
        }
        f4u o; o.v[0] = b0; o.v[1] = b1; o.v[2] = b2; o.v[3] = b3;
        *(f4u*)(SB + (size_t)l * LL + p) = o;
    }
}

// ---------- K5: per-column online softmax stats over SB ----------
__global__ __launch_bounds__(256) void stats2_kernel(const float* __restrict__ SB,
                                                     const float* __restrict__ inorm,
                                                     float* __restrict__ maxc, float* __restrict__ sumc,
                                                     float* __restrict__ wsumc, int bofs) {
    int pt = blockIdx.x, ch = blockIdx.y;
    int lane = threadIdx.x & 63, grp = threadIdx.x >> 6;
    int p = pt * 64 + lane;
    float mx = -1e30f, se = 0.f, ws = 0.f;
    int l0 = ch * (LL / NCH);
    for (int l = l0 + grp; l < l0 + (LL / NCH); l += 4) {
        float bs = SB[(size_t)l * LL + p];
        float in = inorm[bofs + l];
        float nm = fmaxf(mx, bs);
        float r1 = __expf(mx - nm), r2 = __expf(bs - nm);
        se = se * r1 + r2;
        ws = ws * r1 + r2 * in;
        mx = nm;
    }
    __shared__ float smx[4][64], sse[4][64], sws[4][64];
    smx[grp][lane] = mx; sse[grp][lane] = se; sws[grp][lane] = ws;
    __syncthreads();
    if (grp == 0) {
        for (int k = 1; k < 4; ++k) {
            float m2 = smx[k][lane], s2 = sse[k][lane], w2 = sws[k][lane];
            float nm = fmaxf(mx, m2);
            float r1 = __expf(mx - nm), r2 = __expf(m2 - nm);
            se = se * r1 + s2 * r2;
            ws = ws * r1 + w2 * r2;
            mx = nm;
        }
        int idx = ch * LL + p;
        maxc[idx] = mx; sumc[idx] = se; wsumc[idx] = ws;
    }
}

// ---------- K5b: combine chunk stats: adj = max + log(sum); Tp from box of ws/se ----------
__global__ __launch_bounds__(1024) void combine_ttap_kernel(const float* __restrict__ maxc,
                                                            const float* __restrict__ sumc,
                                                            const float* __restrict__ wsumc,
                                                            float* __restrict__ adj,
                                                            float* __restrict__ Tp) {
    __shared__ float bsum[LL];
    int t = threadIdx.x;
    for (int k = 0; k < 4; ++k) {
        int p = t + k * 1024;
        float mx = -1e30f, se = 0.f, ws = 0.f;
        for (int ch = 0; ch < NCH; ++ch) {
            int idx = ch * LL + p;
            float m2 = maxc[idx], s2 = sumc[idx], w2 = wsumc[idx];
            float nm = fmaxf(mx, m2);
            float r1 = __expf(mx - nm), r2 = __expf(m2 - nm);
            se = se * r1 + s2 * r2;
            ws = ws * r1 + w2 * r2;
            mx = nm;
        }
        adj[p] = mx + __logf(se);
        bsum[p] = ws / se;
    }
    __syncthreads();
    for (int k = 0; k < 4; ++k) {
        int p = t + k * 1024;
        int y = p >> 6, x = p & 63;
        float tt = 0.f;
        for (int gy = -1; gy <= 1; ++gy) {
            int yy = y + gy;
            if (yy < 0 || yy >= HH) continue;
            for (int gx = -1; gx <= 1; ++gx) {
                int xx = x + gx;
                if (xx < 0 || xx >= WW) continue;
                tt += bsum[(yy << 6) + xx];
            }
        }
        Tp[p] = tt;
    }
}

// ---------- K7: Nn[l,p] = 9-tap diag sum of exp(SB - adj[p'])*inorm[l'], 4-wide ----------
__global__ __launch_bounds__(256) void bnfuse_kernel(const float* __restrict__ SB,
                                                     const float* __restrict__ adj,
                                                     const float* __restrict__ inorm,
                                                     float* __restrict__ Nn, int bofs) {
    int l = blockIdx.x;
    int i = l >> 6, j = l & 63;
    for (int it = 0; it < 4; ++it) {
        int p = 4 * (threadIdx.x + it * 256);
        int y = p >> 6, x0 = p & 63;
        bool e0 = (x0 == 0), e3 = (x0 == 60);
        float a0 = 0.f, a1 = 0.f, a2 = 0.f, a3 = 0.f;
        #pragma unroll
        for (int di = -1; di <= 1; ++di) {
            int ii = i + di, yy = y + di;
            if ((unsigned)ii >= HH || (unsigned)yy >= HH) continue;
            #pragma unroll
            for (int dj = -1; dj <= 1; ++dj) {
                int jj = j + dj;
                if ((unsigned)jj >= WW) continue;
                int D = di * 64 + dj;
                f4u s = *(const f4u*)(SB + (size_t)(l + D) * LL + (p + D));
                f4u av = *(const f4u*)(adj + p + D);
                float inl = inorm[bofs + l + D];
                float t0 = __expf(s.v[0] - av.v[0]) * inl;
                float t1 = __expf(s.v[1] - av.v[1]) * inl;
                float t2 = __expf(s.v[2] - av.v[2]) * inl;
                float t3 = __expf(s.v[3] - av.v[3]) * inl;
                if (dj == -1) t0 = e0 ? 0.f : t0;
                if (dj == 1)  t3 = e3 ? 0.f : t3;
                a0 += t0; a1 += t1; a2 += t2; a3 += t3;
            }
        }
        f4u o; o.v[0] = a0; o.v[1] = a1; o.v[2] = a2; o.v[3] = a3;
        *(f4u*)(Nn + (size_t)l * LL + p) = o;
    }
}

// ---------- K9a: partial rec = bg @ N over a k-slab (A from bf16 bgH) ----------
__global__ __launch_bounds__(256) void gemm_out_part(const ushort* __restrict__ bgH,
                                                     const float* __restrict__ Nn,
                                                     float* __restrict__ part) {
    __shared__ float As[CC][64];   // 32KB (c,k)
    __shared__ float Ns[64][64];   // 16KB (k,p)
    int pt = blockIdx.x, ks = blockIdx.y;
    int tid = threadIdx.x, col = tid & 63, rb = tid >> 6;
    int tx = tid & 15, ty = tid >> 4;
    float acc[8][4] = {};
    for (int kt = ks * (LL / KS); kt < (ks + 1) * (LL / KS); kt += 64) {
        __syncthreads();
        for (int r = 0; r < CC; r += 4)
            As[r + rb][col] = bf2f(bgH[(size_t)(r + rb) * LL + kt + col]);
        for (int r = 0; r < 64; r += 4)
            Ns[r + rb][col] = Nn[(size_t)(kt + r + rb) * LL + pt * 64 + col];
        __syncthreads();
        #pragma unroll 4
        for (int kk = 0; kk < 64; ++kk) {
            float4 b4 = *(const float4*)&Ns[kk][tx * 4];
            float bv[4] = {b4.x, b4.y, b4.z, b4.w};
            #pragma unroll
            for (int ii = 0; ii < 8; ++ii) {
                float a = As[ty * 8 + ii][kk];
                #pragma unroll
                for (int jj = 0; jj < 4; ++jj)
                    acc[ii][jj] += a * bv[jj];
            }
        }
    }
    for (int ii = 0; ii < 8; ++ii) {
        float4 v = {acc[ii][0], acc[ii][1], acc[ii][2], acc[ii][3]};
        *(float4*)&part[((size_t)ks * CC + ty * 8 + ii) * LL + pt * 64 + tx * 4] = v;
    }
}

// ---------- K9b: combine slabs + epilogue ----------
__global__ void epilogue_kernel(const float* __restrict__ part, const float* __restrict__ Tp,
                                const float* __restrict__ fgb, const float* __restrict__ maskb,
                                float* __restrict__ outb) {
    int g = blockIdx.x * 256 + threadIdx.x;   // C*L
    int p = g & 4095;
    float acc = 0.f;
    for (int ks = 0; ks < KS; ++ks)
        acc += part[(size_t)ks * CC * LL + g];
    float rec = acc + EPSF * Tp[p];
    float mval = maskb[p];
    outb[g] = rec * mval * (1.f / 9.f) + fgb[g] * (1.f - mval);
}

extern "C" void kernel_launch(void* const* d_in, const int* in_sizes, int n_in,
                              void* d_out, int out_size, void* d_ws, size_t ws_size,
                              hipStream_t stream) {
    const float* fg = (const float*)d_in[0];     // [B,C,H,W]
    const float* mask = (const float*)d_in[1];   // [B,1,H,W]
    float* out = (float*)d_out;
    float* ws = (float*)d_ws;

    // ws layout: smalls first (so bufA head-spill lands in allocated memory),
    // then bgH (bf16), then the two LL2 buffers. Total ~133 MiB.
    float* Sfg = ws;                                 // B*LL each:
    float* Sbg = Sfg + BB * LL;
    float* Qq = Sbg + BB * LL;
    float* inorm = Qq + BB * LL;
    float* SfgTap = inorm + BB * LL;
    float* maxc = SfgTap + BB * LL;                  // NCH*LL each:
    float* sumc = maxc + NCH * LL;
    float* wsumc = sumc + NCH * LL;
    float* adj = wsumc + NCH * LL;                   // LL each:
    float* Tp = adj + LL;
    ushort* bgH = (ushort*)(Tp + LL);                // B*CC*LL ushorts (4 MiB)
    float* bufA = (float*)(bgH + (size_t)BB * CC * LL);   // LL2 (M / Nn)
    float* bufB = bufA + LL2;                        // LL2 (SB / part)
    // per-sample transposed bf16 tiles live in the (currently dead) tail of bufB:
    ushort* bgT = (ushort*)(bufB + 8 * 1024 * 1024);
    ushort* fgT = bgT + (size_t)LL * CC;

    prep_kernel<<<BB * LL / 256, 256, 0, stream>>>(fg, mask, Sfg, Sbg, Qq);
    norm_kernel<<<BB * LL / 256, 256, 0, stream>>>(Sfg, Sbg, Qq, inorm, SfgTap);

    for (int b = 0; b < BB; ++b) {
        const float* fgb = fg + (size_t)b * CC * LL;
        const float* mb = mask + (size_t)b * LL;
        ushort* bgHb = bgH + (size_t)b * CC * LL;
        int bofs = b * LL;

        transpose_kernel<<<dim3(64, 2), 256, 0, stream>>>(fgb, mb, fgT, bgT, bgHb);
        gemm_M_mfma<<<dim3(32, 32), 256, 0, stream>>>(bgT, fgT, bufA);
        scoresbox_kernel<<<LL, 256, 0, stream>>>(bufA, SfgTap, inorm, bufB, bofs);
        stats2_kernel<<<dim3(64, NCH), 256, 0, stream>>>(bufB, inorm, maxc, sumc, wsumc, bofs);
        combine_ttap_kernel<<<1, 1024, 0, stream>>>(maxc, sumc, wsumc, adj, Tp);
        bnfuse_kernel<<<LL, 256, 0, stream>>>(bufB, adj, inorm, bufA, bofs);
        gemm_out_part<<<dim3(64, KS), 256, 0, stream>>>(bgHb, bufA, bufB);
        epilogue_kernel<<<CC * LL / 256, 256, 0, stream>>>(bufB, Tp, fgb, mb, out + (size_t)b * CC * LL);
    }
}